// Round 3
// baseline (77.699 us; speedup 1.0000x reference)
//
#include <hip/hip_runtime.h>

// Binary successive-approximation encoder:
//   v = clip(x,0,1); bits are the first n_bits of v's binary-fraction expansion
//   (each reference subtraction is exact in fp32, so floor(v*2^n) reproduces it;
//    v==1.0 fires every bit -> clamp to 2^n-1).
// x: [16,1024,512] f32 -> out: [16,1024,n_bits,512] f32.
// Memory-bound: 33.5 MB in + 335.5 MB out. One thread per 4 floats; all n_bits
// stores are independent (no serial v-chain) -> max MLP. Nontemporal stores:
// output is write-only streaming, skip L2 retention.
// NOTE: __builtin_nontemporal_* requires native clang vector types, not
// HIP_vector_type — use ext_vector_type(4).

#define C_DIM 512

typedef float f32x4 __attribute__((ext_vector_type(4)));

__global__ __launch_bounds__(256) void binenc_kernel(const float* __restrict__ x,
                                                     const int* __restrict__ n_bits_p,
                                                     float* __restrict__ out,
                                                     int n_vec) {
    const int n_bits = *n_bits_p;
    const float scale = (float)(1u << n_bits);
    const int   maxq  = (1 << n_bits) - 1;

    const int vid = blockIdx.x * blockDim.x + threadIdx.x;
    if (vid >= n_vec) return;

    const f32x4 xin = __builtin_nontemporal_load(reinterpret_cast<const f32x4*>(x) + vid);

    const int fidx = vid << 2;          // flat float index
    const int row  = fidx >> 9;         // (b*T + t), C = 512
    const int c    = fidx & (C_DIM - 1);

    int q[4];
#pragma unroll
    for (int j = 0; j < 4; ++j) {
        float v = fminf(fmaxf(xin[j], 0.0f), 1.0f);    // jnp.clip, exact
        int qi = (int)(v * scale);                     // exact pow2 scale + trunc = floor
        q[j] = qi > maxq ? maxq : qi;                  // v==1.0 -> all bits set
    }

    float* outbase = out + row * n_bits * C_DIM + c;
    for (int i = 0; i < n_bits; ++i) {
        const int sh = n_bits - 1 - i;
        f32x4 s;
#pragma unroll
        for (int j = 0; j < 4; ++j)
            s[j] = (float)((q[j] >> sh) & 1);
        __builtin_nontemporal_store(s, reinterpret_cast<f32x4*>(outbase + i * C_DIM));
    }
}

extern "C" void kernel_launch(void* const* d_in, const int* in_sizes, int n_in,
                              void* d_out, int out_size, void* d_ws, size_t ws_size,
                              hipStream_t stream) {
    const float* x        = (const float*)d_in[0];
    const int*   n_bits_p = (const int*)d_in[1];
    float*       out      = (float*)d_out;

    const int n_elems = in_sizes[0];        // 16*1024*512 = 8,388,608
    const int n_vec   = n_elems >> 2;       // float4 granularity
    const int block   = 256;
    const int grid    = (n_vec + block - 1) / block;

    binenc_kernel<<<grid, block, 0, stream>>>(x, n_bits_p, out, n_vec);
}

// Round 4
// 77.226 us; speedup vs baseline: 1.0061x; 1.0061x over previous
//
#include <hip/hip_runtime.h>

// Binary successive-approximation encoder:
//   v = clip(x,0,1); bit i of floor(v*2^n) (clamped to 2^n-1) reproduces the
//   reference's successive subtraction exactly (all pow2 ops exact in fp32).
// x: [16,1024,512] f32 -> out: [16,1024,n_bits,512] f32.
// Memory-bound: 33.5 MB in + 335.5 MB out (~59 us @ 6.3 TB/s).
// R4: persistent grid-stride (2048 blocks x 256 thr = 32 waves/CU resident),
// 4 float4 per thread -> 4x fewer workgroup dispatches, less ramp/tail.
// Plain (cached) loads/stores: input is L3-resident across graph replays;
// nt hints measured neutral-to-negative in R3.

#define C_DIM 512

typedef float f32x4 __attribute__((ext_vector_type(4)));

__global__ __launch_bounds__(256) void binenc_kernel(const float* __restrict__ x,
                                                     const int* __restrict__ n_bits_p,
                                                     float* __restrict__ out,
                                                     int n_vec) {
    const int n_bits = *n_bits_p;
    const float scale = (float)(1u << n_bits);
    const int   maxq  = (1 << n_bits) - 1;

    const int tid    = blockIdx.x * blockDim.x + threadIdx.x;
    const int stride = gridDim.x * blockDim.x;

    for (int vid = tid; vid < n_vec; vid += stride) {
        const f32x4 xin = reinterpret_cast<const f32x4*>(x)[vid];

        const int fidx = vid << 2;          // flat float index
        const int row  = fidx >> 9;         // (b*T + t), C = 512
        const int c    = fidx & (C_DIM - 1);

        int q[4];
#pragma unroll
        for (int j = 0; j < 4; ++j) {
            float v = fminf(fmaxf(xin[j], 0.0f), 1.0f);    // jnp.clip, exact
            int qi = (int)(v * scale);                     // exact pow2 scale+trunc
            q[j] = qi > maxq ? maxq : qi;                  // v==1.0 -> all bits
        }

        float* outbase = out + row * n_bits * C_DIM + c;
#pragma unroll 10
        for (int i = 0; i < n_bits; ++i) {
            const int sh = n_bits - 1 - i;
            f32x4 s;
#pragma unroll
            for (int j = 0; j < 4; ++j)
                s[j] = (float)((q[j] >> sh) & 1);
            reinterpret_cast<f32x4*>(outbase + i * C_DIM)[0] = s;
        }
    }
}

extern "C" void kernel_launch(void* const* d_in, const int* in_sizes, int n_in,
                              void* d_out, int out_size, void* d_ws, size_t ws_size,
                              hipStream_t stream) {
    const float* x        = (const float*)d_in[0];
    const int*   n_bits_p = (const int*)d_in[1];
    float*       out      = (float*)d_out;

    const int n_elems = in_sizes[0];        // 16*1024*512 = 8,388,608
    const int n_vec   = n_elems >> 2;       // float4 granularity
    const int block   = 256;
    // Persistent shape: 8 blocks/CU x 256 CUs = 2048 blocks (32 waves/CU).
    int grid = 2048;
    const int max_grid = (n_vec + block - 1) / block;
    if (grid > max_grid) grid = max_grid;

    binenc_kernel<<<grid, block, 0, stream>>>(x, n_bits_p, out, n_vec);
}

// Round 5
// 73.235 us; speedup vs baseline: 1.0610x; 1.0545x over previous
//
#include <hip/hip_runtime.h>

// Binary successive-approximation encoder:
//   v = clip(x,0,1); bit i of floor(v*2^n) (clamped to 2^n-1) reproduces the
//   reference's successive subtraction exactly (all pow2 ops exact in fp32).
// x: [16,1024,512] f32 -> out: [16,1024,n_bits,512] f32.
//
// R5: LINEAR WRITE STREAM. One block per row (b*T+t); 256 threads.
// Within a row, output float4 index = k*256 + tid  (k = 0..ceil(n_bits/2)-1),
// which decomposes as bit = 2k + (tid>>7), c4 = tid & 127  (since 256 = 2*128).
// => each thread's input float4 (c4) is FIXED across k: 1 load, q computed once,
// then n_bits/2 stores that are byte-sequential within the row, rows sequential
// across blockIdx -> globally monotone write stream, same shape as fillBuffer
// (which sustains ~6.9 TB/s on this chip vs our previous scattered 4.9 TB/s).

#define C_DIM 512
#define C4    128   // C_DIM / 4

typedef float f32x4 __attribute__((ext_vector_type(4)));

__global__ __launch_bounds__(256) void binenc_kernel(const float* __restrict__ x,
                                                     const int* __restrict__ n_bits_p,
                                                     float* __restrict__ out) {
    const int n_bits = *n_bits_p;
    const float scale = (float)(1u << n_bits);
    const int   maxq  = (1 << n_bits) - 1;

    const int row  = blockIdx.x;
    const int tid  = threadIdx.x;
    const int c4   = tid & (C4 - 1);   // this thread's input float4 within the row
    const int bit0 = tid >> 7;         // 0 or 1: which bit parity this thread writes

    // One 16B load per thread; same line hit by the paired thread (tid +/- 128) -> L1.
    const f32x4 xv = reinterpret_cast<const f32x4*>(x)[row * C4 + c4];

    int q[4];
#pragma unroll
    for (int j = 0; j < 4; ++j) {
        float v  = fminf(fmaxf(xv[j], 0.0f), 1.0f);   // jnp.clip, exact
        int   qi = (int)(v * scale);                  // exact pow2 scale + trunc
        q[j] = qi > maxq ? maxq : qi;                 // v==1.0 -> all bits set
    }

    // Row-flat output: float4 slot (k*256 + tid) == bit*128 + c4 with
    // bit = 2k + bit0. Stores walk the row in address order as k increases.
    f32x4* rowbase = reinterpret_cast<f32x4*>(out) + (size_t)row * n_bits * C4;
#pragma unroll 5
    for (int k = 0; 2 * k + bit0 < n_bits; ++k) {
        const int sh = n_bits - 1 - (2 * k + bit0);
        f32x4 s;
#pragma unroll
        for (int j = 0; j < 4; ++j)
            s[j] = (float)((q[j] >> sh) & 1);
        rowbase[k * 256 + tid] = s;
    }
}

extern "C" void kernel_launch(void* const* d_in, const int* in_sizes, int n_in,
                              void* d_out, int out_size, void* d_ws, size_t ws_size,
                              hipStream_t stream) {
    const float* x        = (const float*)d_in[0];
    const int*   n_bits_p = (const int*)d_in[1];
    float*       out      = (float*)d_out;

    const int n_rows = in_sizes[0] / C_DIM;   // 16*1024 = 16384 rows
    const int block  = 256;

    binenc_kernel<<<n_rows, block, 0, stream>>>(x, n_bits_p, out);
}